// Round 1
// baseline (583.302 us; speedup 1.0000x reference)
//
#include <hip/hip_runtime.h>
#include <hip/hip_bf16.h>

#define NTOK   4096
#define DMODEL 1024
#define DFF    4096
#define NEXP   8
#define TOPK   2
#define BM 128
#define BN 128
#define BK 32
#define NSLOT   (NTOK*TOPK)            // 8192
#define MAXSLOT (NSLOT + NEXP*BM)      // 9216
#define MAXTILE (MAXSLOT/BM)           // 72

typedef __attribute__((ext_vector_type(8))) short bf16x8;
typedef __attribute__((ext_vector_type(4))) float f32x4;

__device__ __forceinline__ unsigned short f2bf(float f){
    union { float f; unsigned int u; } v; v.f = f;
    unsigned int r = (v.u + 0x7fffu + ((v.u >> 16) & 1u)) >> 16;
    return (unsigned short)r;
}
__device__ __forceinline__ float bf2f(unsigned short h){
    union { unsigned int u; float f; } v; v.u = ((unsigned int)h) << 16;
    return v.f;
}

// ---------------- fp32 -> bf16 convert (x) ----------------
__global__ __launch_bounds__(256) void k_convert(const float* __restrict__ src,
                                                 unsigned short* __restrict__ dst, int n4)
{
    int i = blockIdx.x*256 + threadIdx.x;
    if(i >= n4) return;
    float4 v = ((const float4*)src)[i];
    ushort4 o;
    o.x = f2bf(v.x); o.y = f2bf(v.y); o.z = f2bf(v.z); o.w = f2bf(v.w);
    ((ushort4*)dst)[i] = o;
}

// ------ fp32 [E][R][C] -> bf16 [E][C][R] transpose-convert (weights to B^T layout) ------
__global__ __launch_bounds__(256) void k_transpose_convert(const float* __restrict__ src,
                                                           unsigned short* __restrict__ dst,
                                                           int R, int C)
{
    __shared__ unsigned short tile[32][33];
    src += (size_t)blockIdx.z * R * C;
    dst += (size_t)blockIdx.z * R * C;
    int c0 = blockIdx.x * 32, r0 = blockIdx.y * 32;
    int tx = threadIdx.x, ty = threadIdx.y;
    #pragma unroll
    for(int i=0;i<4;i++)
        tile[ty + i*8][tx] = f2bf(src[(size_t)(r0 + ty + i*8)*C + c0 + tx]);
    __syncthreads();
    #pragma unroll
    for(int i=0;i<4;i++)
        dst[(size_t)(c0 + ty + i*8)*R + r0 + tx] = tile[tx][ty + i*8];
}

// ---------------- gating: softmax -> top-2 -> renormalize ----------------
__global__ __launch_bounds__(256) void k_gate(const float* __restrict__ x,
                                              const float* __restrict__ Wg,
                                              const float* __restrict__ bg,
                                              int* __restrict__ token_e,
                                              float* __restrict__ token_w,
                                              int* __restrict__ cnt)
{
    int wid = threadIdx.x >> 6, lane = threadIdx.x & 63;
    int t = blockIdx.x * 4 + wid;
    const float* xr = x + (size_t)t * DMODEL;
    float pe[NEXP];
    #pragma unroll
    for(int e=0;e<NEXP;e++) pe[e] = 0.f;
    for(int i=0;i<DMODEL/64;i++){
        int d = i*64 + lane;
        float xv = xr[d];
        const float* wr = Wg + (size_t)d * NEXP;
        #pragma unroll
        for(int e=0;e<NEXP;e++) pe[e] += xv * wr[e];
    }
    #pragma unroll
    for(int off=32; off>0; off>>=1){
        #pragma unroll
        for(int e=0;e<NEXP;e++) pe[e] += __shfl_xor(pe[e], off);
    }
    if(lane == 0){
        float lg[NEXP], mx = -1e30f;
        #pragma unroll
        for(int e=0;e<NEXP;e++){ lg[e] = pe[e] + bg[e]; mx = fmaxf(mx, lg[e]); }
        float pr[NEXP];
        #pragma unroll
        for(int e=0;e<NEXP;e++) pr[e] = expf(lg[e] - mx);
        int e0 = 0; float p0 = pr[0];
        #pragma unroll
        for(int e=1;e<NEXP;e++) if(pr[e] > p0){ p0 = pr[e]; e0 = e; }
        int e1 = -1; float p1 = -1.f;
        #pragma unroll
        for(int e=0;e<NEXP;e++) if(e != e0 && pr[e] > p1){ p1 = pr[e]; e1 = e; }
        float dn = p0 + p1;
        token_e[2*t]   = e0; token_w[2*t]   = p0/dn;
        token_e[2*t+1] = e1; token_w[2*t+1] = p1/dn;
        atomicAdd(&cnt[e0], 1); atomicAdd(&cnt[e1], 1);
    }
}

// ---------------- prefix: expert bases (128-aligned) + tile table ----------------
__global__ void k_prefix(const int* __restrict__ cnt, int* __restrict__ base,
                         int* __restrict__ cursor, int* __restrict__ tile_e,
                         int* __restrict__ tile_row0, int* __restrict__ tile_valid)
{
    if(threadIdx.x != 0 || blockIdx.x != 0) return;
    int off = 0, nt = 0;
    for(int e=0;e<NEXP;e++){
        base[e] = off; cursor[e] = 0;
        int c = cnt[e];
        for(int r=0;r<c;r+=BM){
            tile_e[nt] = e; tile_row0[nt] = off + r;
            tile_valid[nt] = (c - r < BM) ? (c - r) : BM;
            nt++;
        }
        off += ((c + BM - 1)/BM)*BM;
    }
    for(int i=nt;i<MAXTILE;i++){ tile_e[i]=0; tile_row0[i]=0; tile_valid[i]=0; }
}

// ---------------- scatter tokens into expert slot lists ----------------
__global__ __launch_bounds__(256) void k_scatter(const int* __restrict__ token_e,
                                                 const float* __restrict__ token_w,
                                                 const int* __restrict__ base,
                                                 int* __restrict__ cursor,
                                                 int* __restrict__ slot_token,
                                                 float* __restrict__ slot_w,
                                                 int* __restrict__ slot_of)
{
    int i = blockIdx.x*256 + threadIdx.x;
    if(i >= NSLOT) return;
    int e = token_e[i];
    int s = base[e] + atomicAdd(&cursor[e], 1);
    slot_token[s] = i >> 1;
    slot_w[s] = token_w[i];
    slot_of[i] = s;
}

// ---------------- grouped GEMM tile kernel ----------------
// A: bf16, lda == K. GATHER: A row r -> slot_token[row0+r] (X). else A row = row0+r (H).
// B: bf16 [E][N][K] (pre-transposed). Out bf16 [slot][N].
// GELU epilogue: out = gelu(acc + bias). else: out = slot_w[row] * (acc + bias).
template<bool GATHER, bool GELU>
__global__ __launch_bounds__(256) void k_gemm(const unsigned short* __restrict__ A,
                                              const unsigned short* __restrict__ Bw,
                                              const float* __restrict__ bias,
                                              const int* __restrict__ tile_e,
                                              const int* __restrict__ tile_row0,
                                              const int* __restrict__ tile_valid,
                                              const int* __restrict__ slot_token,
                                              const float* __restrict__ slot_w,
                                              unsigned short* __restrict__ Out,
                                              int K, int N)
{
    int tid = blockIdx.x;
    int valid = tile_valid[tid];
    if(valid == 0) return;
    int e = tile_e[tid];
    int row0 = tile_row0[tid];
    int n0 = blockIdx.y * BN;
    const unsigned short* Be = Bw + (size_t)e * N * K;

    __shared__ __align__(16) unsigned short As[BM][BK+8];
    __shared__ __align__(16) unsigned short Bs[BN][BK+8];

    int t = threadIdx.x;
    int lane = t & 63;
    int wid = t >> 6;
    int wr = wid >> 1, wc = wid & 1;

    const unsigned short* aptr[2];
    bool av[2];
    #pragma unroll
    for(int pss=0;pss<2;pss++){
        int r = pss*64 + (t>>2);
        bool v = r < valid;
        av[pss] = v;
        size_t rowoff = 0;
        if(v){
            if(GATHER) rowoff = (size_t)slot_token[row0 + r] * (size_t)K;
            else       rowoff = (size_t)(row0 + r) * (size_t)K;
        }
        aptr[pss] = A + rowoff;
    }
    int scol = (t & 3) * 8;

    f32x4 acc[4][4];
    #pragma unroll
    for(int m=0;m<4;m++)
        #pragma unroll
        for(int n=0;n<4;n++)
            acc[m][n] = (f32x4){0.f,0.f,0.f,0.f};

    for(int k0=0;k0<K;k0+=BK){
        #pragma unroll
        for(int pss=0;pss<2;pss++){
            int r = pss*64 + (t>>2);
            uint4 va = {0u,0u,0u,0u};
            if(av[pss]) va = *(const uint4*)(aptr[pss] + k0 + scol);
            *(uint4*)&As[r][scol] = va;
            uint4 vb = *(const uint4*)(Be + (size_t)(n0 + r)*K + k0 + scol);
            *(uint4*)&Bs[r][scol] = vb;
        }
        __syncthreads();
        bf16x8 af[4], bfr[4];
        int kk = (lane >> 4) * 8;
        int rl = lane & 15;
        #pragma unroll
        for(int m=0;m<4;m++) af[m] = *(const bf16x8*)&As[wr*64 + m*16 + rl][kk];
        #pragma unroll
        for(int n=0;n<4;n++) bfr[n] = *(const bf16x8*)&Bs[wc*64 + n*16 + rl][kk];
        #pragma unroll
        for(int m=0;m<4;m++)
            #pragma unroll
            for(int n=0;n<4;n++)
                acc[m][n] = __builtin_amdgcn_mfma_f32_16x16x32_bf16(af[m], bfr[n], acc[m][n], 0, 0, 0);
        __syncthreads();
    }

    const float* be = bias + (size_t)e * N;
    #pragma unroll
    for(int m=0;m<4;m++){
        int rb = wr*64 + m*16 + ((lane>>4)<<2);
        #pragma unroll
        for(int j=0;j<4;j++){
            int r = rb + j;
            if(r >= valid) continue;
            size_t grow = (size_t)(row0 + r);
            float wsc = GELU ? 0.f : slot_w[grow];
            #pragma unroll
            for(int n=0;n<4;n++){
                int col = n0 + wc*64 + n*16 + (lane & 15);
                float v = acc[m][n][j] + be[col];
                if(GELU) v = 0.5f * v * (1.f + erff(v * 0.70710678118654752f));
                else     v *= wsc;
                Out[grow * (size_t)N + col] = f2bf(v);
            }
        }
    }
}

// ---------------- combine: out[t] = Y[slot0] + Y[slot1] (already gate-scaled) ----------------
__global__ __launch_bounds__(256) void k_combine(const int* __restrict__ slot_of,
                                                 const unsigned short* __restrict__ Y,
                                                 float* __restrict__ out)
{
    int i = blockIdx.x*256 + threadIdx.x;
    int t  = i >> 8;          // DMODEL/4 = 256 float4 groups per token
    int cg = i & 255;
    int s0 = slot_of[2*t], s1 = slot_of[2*t+1];
    uint2 a = *((const uint2*)(Y + (size_t)s0*DMODEL) + cg);
    uint2 b = *((const uint2*)(Y + (size_t)s1*DMODEL) + cg);
    float4 o;
    o.x = bf2f((unsigned short)(a.x & 0xffffu)) + bf2f((unsigned short)(b.x & 0xffffu));
    o.y = bf2f((unsigned short)(a.x >> 16))     + bf2f((unsigned short)(b.x >> 16));
    o.z = bf2f((unsigned short)(a.y & 0xffffu)) + bf2f((unsigned short)(b.y & 0xffffu));
    o.w = bf2f((unsigned short)(a.y >> 16))     + bf2f((unsigned short)(b.y >> 16));
    *((float4*)(out + (size_t)t*DMODEL) + cg) = o;
}

extern "C" void kernel_launch(void* const* d_in, const int* in_sizes, int n_in,
                              void* d_out, int out_size, void* d_ws, size_t ws_size,
                              hipStream_t stream)
{
    const float* x  = (const float*)d_in[0];
    const float* W1 = (const float*)d_in[1];
    const float* b1 = (const float*)d_in[2];
    const float* W2 = (const float*)d_in[3];
    const float* b2 = (const float*)d_in[4];
    const float* Wg = (const float*)d_in[5];
    const float* bg = (const float*)d_in[6];
    float* out = (float*)d_out;

    char* p = (char*)d_ws;
    auto alloc = [&](size_t bytes)->char*{
        char* r = p; p += (bytes + 255) & ~(size_t)255; return r;
    };
    unsigned short* W1t = (unsigned short*)alloc((size_t)NEXP*DFF*DMODEL*2);   // [E][DFF][DMODEL]
    unsigned short* W2t = (unsigned short*)alloc((size_t)NEXP*DMODEL*DFF*2);   // [E][DMODEL][DFF]
    unsigned short* Xb  = (unsigned short*)alloc((size_t)NTOK*DMODEL*2);
    unsigned short* H   = (unsigned short*)alloc((size_t)MAXSLOT*DFF*2);
    unsigned short* Y   = (unsigned short*)alloc((size_t)MAXSLOT*DMODEL*2);
    int*   slot_token = (int*)alloc(MAXSLOT*4);
    float* slot_w     = (float*)alloc(MAXSLOT*4);
    int*   slot_of    = (int*)alloc(NSLOT*4);
    int*   token_e    = (int*)alloc(NSLOT*4);
    float* token_w    = (float*)alloc(NSLOT*4);
    int*   cnt    = (int*)alloc(32);
    int*   base   = (int*)alloc(32);
    int*   cursor = (int*)alloc(32);
    int*   tile_e     = (int*)alloc(MAXTILE*4);
    int*   tile_row0  = (int*)alloc(MAXTILE*4);
    int*   tile_valid = (int*)alloc(MAXTILE*4);
    (void)ws_size; (void)in_sizes; (void)n_in; (void)out_size;

    hipMemsetAsync(cnt, 0, 32, stream);
    k_convert<<<(NTOK*DMODEL/4 + 255)/256, 256, 0, stream>>>(x, Xb, NTOK*DMODEL/4);
    dim3 tb(32, 8);
    k_transpose_convert<<<dim3(DFF/32, DMODEL/32, NEXP), tb, 0, stream>>>(W1, W1t, DMODEL, DFF);
    k_transpose_convert<<<dim3(DMODEL/32, DFF/32, NEXP), tb, 0, stream>>>(W2, W2t, DFF, DMODEL);
    k_gate<<<NTOK/4, 256, 0, stream>>>(x, Wg, bg, token_e, token_w, cnt);
    k_prefix<<<1, 64, 0, stream>>>(cnt, base, cursor, tile_e, tile_row0, tile_valid);
    k_scatter<<<NSLOT/256, 256, 0, stream>>>(token_e, token_w, base, cursor,
                                             slot_token, slot_w, slot_of);
    k_gemm<true, true ><<<dim3(MAXTILE, DFF/BN),    256, 0, stream>>>(
        Xb, W1t, b1, tile_e, tile_row0, tile_valid, slot_token, slot_w, H, DMODEL, DFF);
    k_gemm<false,false><<<dim3(MAXTILE, DMODEL/BN), 256, 0, stream>>>(
        H,  W2t, b2, tile_e, tile_row0, tile_valid, slot_token, slot_w, Y, DFF, DMODEL);
    k_combine<<<NTOK*DMODEL/4/256, 256, 0, stream>>>(slot_of, Y, out);
}

// Round 2
// 496.057 us; speedup vs baseline: 1.1759x; 1.1759x over previous
//
#include <hip/hip_runtime.h>
#include <hip/hip_bf16.h>

#define NTOK   4096
#define DMODEL 1024
#define DFF    4096
#define NEXP   8
#define TOPK   2
#define BM 128
#define BN 128
#define BK 64
#define NSLOT   (NTOK*TOPK)            // 8192
#define MAXSLOT (NSLOT + NEXP*BM)      // 9216
#define MAXTILE (MAXSLOT/BM)           // 72

typedef __attribute__((ext_vector_type(8))) short bf16x8;
typedef __attribute__((ext_vector_type(4))) float f32x4;

__device__ __forceinline__ unsigned short f2bf(float f){
    union { float f; unsigned int u; } v; v.f = f;
    unsigned int r = (v.u + 0x7fffu + ((v.u >> 16) & 1u)) >> 16;
    return (unsigned short)r;
}
__device__ __forceinline__ float bf2f(unsigned short h){
    union { unsigned int u; float f; } v; v.u = ((unsigned int)h) << 16;
    return v.f;
}

// async global->LDS, 16B per lane. LDS dest must be wave-uniform base + lane*16.
__device__ __forceinline__ void gload16(const unsigned short* g, unsigned short* l){
    __builtin_amdgcn_global_load_lds(
        (const __attribute__((address_space(1))) void*)g,
        (__attribute__((address_space(3))) void*)l,
        16, 0, 0);
}

// ---------------- fp32 -> bf16 convert (x) ----------------
__global__ __launch_bounds__(256) void k_convert(const float* __restrict__ src,
                                                 unsigned short* __restrict__ dst, int n4)
{
    int i = blockIdx.x*256 + threadIdx.x;
    if(i >= n4) return;
    float4 v = ((const float4*)src)[i];
    ushort4 o;
    o.x = f2bf(v.x); o.y = f2bf(v.y); o.z = f2bf(v.z); o.w = f2bf(v.w);
    ((ushort4*)dst)[i] = o;
}

// ------ fp32 [E][R][C] -> bf16 [E][C][R] transpose-convert (weights to B^T layout) ------
// 64x64 tiles, float4 loads (16B/lane), ushort4 stores (8B/lane)
__global__ __launch_bounds__(256) void k_transpose_convert(const float* __restrict__ src,
                                                           unsigned short* __restrict__ dst,
                                                           int R, int C)
{
    __shared__ unsigned short tile[64][72];
    src += (size_t)blockIdx.z * R * C;
    dst += (size_t)blockIdx.z * R * C;
    int r0 = blockIdx.y * 64, c0 = blockIdx.x * 64;
    int t = threadIdx.x;
    int tr = t >> 4;          // 0..15
    int tc = (t & 15) * 4;    // 0..60
    #pragma unroll
    for(int i=0;i<4;i++){
        float4 v = *(const float4*)&src[(size_t)(r0 + tr + i*16)*C + c0 + tc];
        tile[tc+0][tr + i*16] = f2bf(v.x);
        tile[tc+1][tr + i*16] = f2bf(v.y);
        tile[tc+2][tr + i*16] = f2bf(v.z);
        tile[tc+3][tr + i*16] = f2bf(v.w);
    }
    __syncthreads();
    #pragma unroll
    for(int i=0;i<4;i++){
        ushort4 o;
        o.x = tile[tr + i*16][tc+0];
        o.y = tile[tr + i*16][tc+1];
        o.z = tile[tr + i*16][tc+2];
        o.w = tile[tr + i*16][tc+3];
        *(ushort4*)&dst[(size_t)(c0 + tr + i*16)*R + r0 + tc] = o;
    }
}

// ---------------- gating: softmax -> top-2 -> renormalize ----------------
__global__ __launch_bounds__(256) void k_gate(const float* __restrict__ x,
                                              const float* __restrict__ Wg,
                                              const float* __restrict__ bg,
                                              int* __restrict__ token_e,
                                              float* __restrict__ token_w,
                                              int* __restrict__ cnt)
{
    int wid = threadIdx.x >> 6, lane = threadIdx.x & 63;
    int t = blockIdx.x * 4 + wid;
    const float* xr = x + (size_t)t * DMODEL;
    float pe[NEXP];
    #pragma unroll
    for(int e=0;e<NEXP;e++) pe[e] = 0.f;
    for(int i=0;i<DMODEL/64;i++){
        int d = i*64 + lane;
        float xv = xr[d];
        const float* wr = Wg + (size_t)d * NEXP;
        #pragma unroll
        for(int e=0;e<NEXP;e++) pe[e] += xv * wr[e];
    }
    #pragma unroll
    for(int off=32; off>0; off>>=1){
        #pragma unroll
        for(int e=0;e<NEXP;e++) pe[e] += __shfl_xor(pe[e], off);
    }
    if(lane == 0){
        float lg[NEXP], mx = -1e30f;
        #pragma unroll
        for(int e=0;e<NEXP;e++){ lg[e] = pe[e] + bg[e]; mx = fmaxf(mx, lg[e]); }
        float pr[NEXP];
        #pragma unroll
        for(int e=0;e<NEXP;e++) pr[e] = expf(lg[e] - mx);
        int e0 = 0; float p0 = pr[0];
        #pragma unroll
        for(int e=1;e<NEXP;e++) if(pr[e] > p0){ p0 = pr[e]; e0 = e; }
        int e1 = -1; float p1 = -1.f;
        #pragma unroll
        for(int e=0;e<NEXP;e++) if(e != e0 && pr[e] > p1){ p1 = pr[e]; e1 = e; }
        float dn = p0 + p1;
        token_e[2*t]   = e0; token_w[2*t]   = p0/dn;
        token_e[2*t+1] = e1; token_w[2*t+1] = p1/dn;
        atomicAdd(&cnt[e0], 1); atomicAdd(&cnt[e1], 1);
    }
}

// ---------------- prefix: expert bases (128-aligned) + tile table ----------------
__global__ void k_prefix(const int* __restrict__ cnt, int* __restrict__ base,
                         int* __restrict__ cursor, int* __restrict__ tile_e,
                         int* __restrict__ tile_row0, int* __restrict__ tile_valid)
{
    if(threadIdx.x != 0 || blockIdx.x != 0) return;
    int off = 0, nt = 0;
    for(int e=0;e<NEXP;e++){
        base[e] = off; cursor[e] = 0;
        int c = cnt[e];
        for(int r=0;r<c;r+=BM){
            tile_e[nt] = e; tile_row0[nt] = off + r;
            tile_valid[nt] = (c - r < BM) ? (c - r) : BM;
            nt++;
        }
        off += ((c + BM - 1)/BM)*BM;
    }
    for(int i=nt;i<MAXTILE;i++){ tile_e[i]=0; tile_row0[i]=0; tile_valid[i]=0; }
}

// ---------------- scatter tokens into expert slot lists ----------------
__global__ __launch_bounds__(256) void k_scatter(const int* __restrict__ token_e,
                                                 const float* __restrict__ token_w,
                                                 const int* __restrict__ base,
                                                 int* __restrict__ cursor,
                                                 int* __restrict__ slot_token,
                                                 float* __restrict__ slot_w,
                                                 int* __restrict__ slot_of)
{
    int i = blockIdx.x*256 + threadIdx.x;
    if(i >= NSLOT) return;
    int e = token_e[i];
    int s = base[e] + atomicAdd(&cursor[e], 1);
    slot_token[s] = i >> 1;
    slot_w[s] = token_w[i];
    slot_of[i] = s;
}

// ---------------- grouped GEMM tile kernel (m97 structure) ----------------
// A: bf16, lda == K. GATHER: A row r -> slot_token[row0+r]. else A row = row0+r.
// B: bf16 [E][N][K] (pre-transposed). Out bf16 [slot][N].
// LDS: linear [128][BK] bf16, XOR chunk-swizzled content via pre-swizzled global src
// (rule 21: linear dest + inverse-swz source + swz on read).
template<bool GATHER, bool GELU>
__global__ __launch_bounds__(256) void k_gemm(const unsigned short* __restrict__ A,
                                              const unsigned short* __restrict__ Bw,
                                              const float* __restrict__ bias,
                                              const int* __restrict__ tile_e,
                                              const int* __restrict__ tile_row0,
                                              const int* __restrict__ tile_valid,
                                              const int* __restrict__ slot_token,
                                              const float* __restrict__ slot_w,
                                              unsigned short* __restrict__ Out,
                                              int K, int N)
{
    int tid = blockIdx.x;
    int valid = tile_valid[tid];
    if(valid == 0) return;
    int e = tile_e[tid];
    int row0 = tile_row0[tid];
    int n0 = blockIdx.y * BN;
    const unsigned short* Be = Bw + (size_t)e * N * K;

    __shared__ unsigned short As[BM*BK];
    __shared__ unsigned short Bs[BN*BK];

    int t = threadIdx.x;
    int lane = t & 63;
    int wid = t >> 6;
    int wr = wid >> 1, wc = wid & 1;

    // --- staging setup: thread t, issue i stages LDS chunk p = i*256+t (16B chunks)
    // row r = i*32 + (t>>3), chunk col c = t&7; content = global chunk c ^ (r&7)
    int srow = t >> 3;                      // 0..31
    int csw  = (t & 7) ^ (srow & 7);        // swizzled source chunk (r&7 == srow&7 for all i)
    const unsigned short* arow[4];
    const unsigned short* brow[4];
    #pragma unroll
    for(int i=0;i<4;i++){
        int r = i*32 + srow;
        size_t aoff;
        if(GATHER) aoff = (size_t)slot_token[row0 + r] * (size_t)K;
        else       aoff = (size_t)(row0 + r) * (size_t)K;
        arow[i] = A  + aoff + csw*8;
        brow[i] = Be + (size_t)(n0 + r)*K + csw*8;
    }
    unsigned short* alds = As + (size_t)t * 8;
    unsigned short* blds = Bs + (size_t)t * 8;

    f32x4 acc[4][4];
    #pragma unroll
    for(int m=0;m<4;m++)
        #pragma unroll
        for(int n=0;n<4;n++)
            acc[m][n] = (f32x4){0.f,0.f,0.f,0.f};

    int rl = lane & 15;
    int g  = lane >> 4;
    int rx = rl & 7;

    for(int k0=0;k0<K;k0+=BK){
        __syncthreads();   // previous compute done before LDS overwrite
        #pragma unroll
        for(int i=0;i<4;i++){
            gload16(arow[i] + k0, alds + i*2048);
            gload16(brow[i] + k0, blds + i*2048);
        }
        __syncthreads();   // compiler drains vmcnt(0) before barrier -> tile ready

        #pragma unroll
        for(int kb=0;kb<2;kb++){
            int sw = ((kb*4 + g) ^ rx) * 8;   // swizzled chunk offset (shorts)
            bf16x8 af[4], bfv[4];
            #pragma unroll
            for(int m=0;m<4;m++) af[m]  = *(const bf16x8*)&As[(wr*64 + m*16 + rl)*BK + sw];
            #pragma unroll
            for(int n=0;n<4;n++) bfv[n] = *(const bf16x8*)&Bs[(wc*64 + n*16 + rl)*BK + sw];
            #pragma unroll
            for(int m=0;m<4;m++)
                #pragma unroll
                for(int n=0;n<4;n++)
                    acc[m][n] = __builtin_amdgcn_mfma_f32_16x16x32_bf16(af[m], bfv[n], acc[m][n], 0, 0, 0);
        }
    }

    const float* be = bias + (size_t)e * N;
    #pragma unroll
    for(int m=0;m<4;m++){
        int rb = wr*64 + m*16 + ((lane>>4)<<2);
        #pragma unroll
        for(int j=0;j<4;j++){
            int r = rb + j;
            if(r >= valid) continue;
            size_t grow = (size_t)(row0 + r);
            float wsc = GELU ? 0.f : slot_w[grow];
            #pragma unroll
            for(int n=0;n<4;n++){
                int col = n0 + wc*64 + n*16 + (lane & 15);
                float v = acc[m][n][j] + be[col];
                if(GELU) v = 0.5f * v * (1.f + erff(v * 0.70710678118654752f));
                else     v *= wsc;
                Out[grow * (size_t)N + col] = f2bf(v);
            }
        }
    }
}

// ---------------- combine: out[t] = Y[slot0] + Y[slot1] (already gate-scaled) ----------------
__global__ __launch_bounds__(256) void k_combine(const int* __restrict__ slot_of,
                                                 const unsigned short* __restrict__ Y,
                                                 float* __restrict__ out)
{
    int i = blockIdx.x*256 + threadIdx.x;
    int t  = i >> 8;          // DMODEL/4 = 256 float4 groups per token
    int cg = i & 255;
    int s0 = slot_of[2*t], s1 = slot_of[2*t+1];
    uint2 a = *((const uint2*)(Y + (size_t)s0*DMODEL) + cg);
    uint2 b = *((const uint2*)(Y + (size_t)s1*DMODEL) + cg);
    float4 o;
    o.x = bf2f((unsigned short)(a.x & 0xffffu)) + bf2f((unsigned short)(b.x & 0xffffu));
    o.y = bf2f((unsigned short)(a.x >> 16))     + bf2f((unsigned short)(b.x >> 16));
    o.z = bf2f((unsigned short)(a.y & 0xffffu)) + bf2f((unsigned short)(b.y & 0xffffu));
    o.w = bf2f((unsigned short)(a.y >> 16))     + bf2f((unsigned short)(b.y >> 16));
    *((float4*)(out + (size_t)t*DMODEL) + cg) = o;
}

extern "C" void kernel_launch(void* const* d_in, const int* in_sizes, int n_in,
                              void* d_out, int out_size, void* d_ws, size_t ws_size,
                              hipStream_t stream)
{
    const float* x  = (const float*)d_in[0];
    const float* W1 = (const float*)d_in[1];
    const float* b1 = (const float*)d_in[2];
    const float* W2 = (const float*)d_in[3];
    const float* b2 = (const float*)d_in[4];
    const float* Wg = (const float*)d_in[5];
    const float* bg = (const float*)d_in[6];
    float* out = (float*)d_out;

    char* p = (char*)d_ws;
    auto alloc = [&](size_t bytes)->char*{
        char* r = p; p += (bytes + 255) & ~(size_t)255; return r;
    };
    unsigned short* W1t = (unsigned short*)alloc((size_t)NEXP*DFF*DMODEL*2);   // [E][DFF][DMODEL]
    unsigned short* W2t = (unsigned short*)alloc((size_t)NEXP*DMODEL*DFF*2);   // [E][DMODEL][DFF]
    unsigned short* Xb  = (unsigned short*)alloc((size_t)NTOK*DMODEL*2);
    unsigned short* H   = (unsigned short*)alloc((size_t)MAXSLOT*DFF*2);
    unsigned short* Y   = (unsigned short*)alloc((size_t)MAXSLOT*DMODEL*2);
    int*   slot_token = (int*)alloc(MAXSLOT*4);
    float* slot_w     = (float*)alloc(MAXSLOT*4);
    int*   slot_of    = (int*)alloc(NSLOT*4);
    int*   token_e    = (int*)alloc(NSLOT*4);
    float* token_w    = (float*)alloc(NSLOT*4);
    int*   cnt    = (int*)alloc(32);
    int*   base   = (int*)alloc(32);
    int*   cursor = (int*)alloc(32);
    int*   tile_e     = (int*)alloc(MAXTILE*4);
    int*   tile_row0  = (int*)alloc(MAXTILE*4);
    int*   tile_valid = (int*)alloc(MAXTILE*4);
    (void)ws_size; (void)in_sizes; (void)n_in; (void)out_size;

    hipMemsetAsync(cnt, 0, 32, stream);
    hipMemsetAsync(slot_token, 0, MAXSLOT*4, stream);   // padded rows gather token 0 (safe addr)
    k_convert<<<(NTOK*DMODEL/4 + 255)/256, 256, 0, stream>>>(x, Xb, NTOK*DMODEL/4);
    k_transpose_convert<<<dim3(DFF/64, DMODEL/64, NEXP), 256, 0, stream>>>(W1, W1t, DMODEL, DFF);
    k_transpose_convert<<<dim3(DMODEL/64, DFF/64, NEXP), 256, 0, stream>>>(W2, W2t, DFF, DMODEL);
    k_gate<<<NTOK/4, 256, 0, stream>>>(x, Wg, bg, token_e, token_w, cnt);
    k_prefix<<<1, 64, 0, stream>>>(cnt, base, cursor, tile_e, tile_row0, tile_valid);
    k_scatter<<<NSLOT/256, 256, 0, stream>>>(token_e, token_w, base, cursor,
                                             slot_token, slot_w, slot_of);
    k_gemm<true, true ><<<dim3(MAXTILE, DFF/BN),    256, 0, stream>>>(
        Xb, W1t, b1, tile_e, tile_row0, tile_valid, slot_token, slot_w, H, DMODEL, DFF);
    k_gemm<false,false><<<dim3(MAXTILE, DMODEL/BN), 256, 0, stream>>>(
        H,  W2t, b2, tile_e, tile_row0, tile_valid, slot_token, slot_w, Y, DFF, DMODEL);
    k_combine<<<NTOK*DMODEL/4/256, 256, 0, stream>>>(slot_of, Y, out);
}